// Round 9
// baseline (178.500 us; speedup 1.0000x reference)
//
#include <hip/hip_runtime.h>
#include <hip/hip_bf16.h>
#include <stdint.h>

// CKA loss via algebraic reduction:
//   HSIC_ij = ||Xi^T Xj||_F^2 - <d_i,d_j> - 2N<r_i,r_j> + N^2 t_i t_j
// Heavy part: 21 fp8 MFMA GEMMs [512x4096]x[4096x512], Frobenius-reduced.
//
// R9: R8's gemm+stats fusion regressed the gemm dispatch 44->80 us (cause
// unexplained -> reverted per discipline). This round: gemm kernel restored
// BYTE-IDENTICAL to R7 (43.9 us, MfmaUtil 33%); stats is its own 24-block
// kernel; tail keeps R8's fused diagred+pairdots+counter-finalize. 4
// dispatches (R7: 6, R8: 3). Tests the "stats branch contaminated the hot
// loop" theory: gemm should return to ~44 us.

#define NPTS  4096
#define DF    512
#define ML    6
#define NPAIR 21
#define BKB   128                // K-bytes per LDS tile row (= 128 fp8 elems)
#define KCHUNK_O 512             // off-diag split-K=8 -> 4 iters
#define KCHUNK_D 1024            // diag split-K=4 -> 8 iters
#define NDIAGBLK 240             // 6 layers x 10 unique tiles x 4 z
#define NOFFBLK  960             // 15 pairs x 8 tiles x 8 z
#define NGEMMBLK (NDIAGBLK + NOFFBLK)
#define NSTATS   24              // 6 layers x 4 n-chunks of 1024
#define NTAIL    81              // 60 diagred + 21 pairdots

typedef float  f32x4 __attribute__((ext_vector_type(4)));
typedef unsigned char u8;
typedef long long i64;

__constant__ int c_PI[NPAIR] = {0,0,0,0,0,0, 1,1,1,1,1, 2,2,2,2, 3,3,3, 4,4, 5};
__constant__ int c_PJ[NPAIR] = {0,1,2,3,4,5, 1,2,3,4,5, 2,3,4,5, 3,4,5, 4,5, 5};
__constant__ int c_DIAGP[ML]  = {0, 6, 11, 15, 18, 20};     // p for (i,i)
__constant__ int c_OFFP[15]   = {1,2,3,4,5, 7,8,9,10, 12,13,14, 16,17, 19};
__constant__ int c_TM[10] = {0,0,0,0, 1,1,1, 2,2, 3};       // upper-tri 4x4
__constant__ int c_TN[10] = {0,1,2,3, 1,2,3, 2,3, 3};

// ---- workspace layout (bytes) ----
#define OFF_XT8 0u                        // 6*512*4096   = 12582912
#define OFF_CP  12582912u                 // 60*4*64KB    = 15728640
#define OFF_SP  28311552u                 // 6*64*512*4   = 786432 (col-sum partials)
#define OFF_DVP 29097984u                 // 6*8*4096*4   = 786432 (row-sq partials)
#define OFF_S   29884416u                 // 12288
#define OFF_F   29896704u                 // 21 floats; cnt at +256
#define OFF_D   29897216u                 // 98304 (dv)
#define OFF_XS  29995520u                 // 98304
#define OFF_DD  30093824u
#define OFF_RD  30094080u
#define OFF_T   30094336u
// total ~30.1 MB

__device__ __forceinline__ unsigned short f2fp8x2(float a, float b) {
    return (unsigned short)(__builtin_amdgcn_cvt_pk_fp8_f32(a, b, 0, false) & 0xffff);
}

__device__ __forceinline__ void gl2lds16(const void* g, void* l) {
    __builtin_amdgcn_global_load_lds(
        (__attribute__((address_space(1))) void*)g,
        (__attribute__((address_space(3))) void*)l, 16, 0, 0);
}

// ------- K1: transpose + fp32->fp8 + partial stats (no atomics) --------------
// X[l][n][d] -> Xt8[l][d][n] (e4m3). sp[(l*64+nt)*512+d] col-sum partial,
// dvp[(l*8+dt)*4096+n] row-sq partial. Block 0 zeroes F + counter.
__global__ __launch_bounds__(256) void k_transpose(const float* __restrict__ X,
                                                   u8* __restrict__ Xt8,
                                                   float* __restrict__ sp,
                                                   float* __restrict__ dvp,
                                                   float* __restrict__ F,
                                                   unsigned* __restrict__ cnt) {
    __shared__ float tT[64][67];
    int nt = blockIdx.x, dt = blockIdx.y, l = blockIdx.z;
    int n0 = nt * 64, d0 = dt * 64;
    int t = threadIdx.x, q = t & 15, r = t >> 4;           // q: d-quad, r: n-row
    if (nt == 0 && dt == 0 && l == 0) {
        if (t >= 128 && t < 128 + NPAIR) F[t - 128] = 0.f;
        if (t == 155) *cnt = 0u;
    }
    const float4* src = (const float4*)(X + ((size_t)l * NPTS + n0) * DF + d0);
#pragma unroll
    for (int p = 0; p < 4; ++p) {
        int rr = r + 16 * p;
        float4 v = src[(size_t)rr * (DF / 4) + q];
        tT[4 * q + 0][rr] = v.x;
        tT[4 * q + 1][rr] = v.y;
        tT[4 * q + 2][rr] = v.z;
        tT[4 * q + 3][rr] = v.w;
    }
    __syncthreads();
    if (t < 64) {                        // column sums over n (d = t)
        float cs = 0.f;
#pragma unroll
        for (int k = 0; k < 64; ++k) {
            int n = (6 * t + k) & 63;    // rotation -> 2-way banks
            cs += tT[t][n];
        }
        sp[((l << 6) + nt) * DF + d0 + t] = cs;
    } else if (t < 128) {                // row sums of squares over d (n = t-64)
        int n = t - 64;
        float rs = 0.f;
#pragma unroll
        for (int d = 0; d < 64; ++d) { float v = tT[d][n]; rs += v * v; }
        dvp[((l << 3) + dt) * NPTS + n0 + n] = rs;
    }
    // write phase: thread -> (dcol = t>>2, 16 n's) packed as uint4 of fp8
    int dcol = t >> 2, nb = (t & 3) * 16;
    uint4 o;
#pragma unroll
    for (int w2 = 0; w2 < 4; ++w2) {
        int j = nb + w2 * 4;
        unsigned lo = f2fp8x2(tT[dcol][j + 0], tT[dcol][j + 1]);
        unsigned hi = f2fp8x2(tT[dcol][j + 2], tT[dcol][j + 3]);
        ((unsigned*)&o)[w2] = lo | (hi << 16);
    }
    *(uint4*)(Xt8 + ((size_t)(l * DF + d0 + dcol)) * NPTS + n0 + nb) = o;
}

// ------- K2: stats: reduce sp->s, dvp->dv, xs = Xt8 . s ----------------------
// grid (24): sid = (l, n-chunk of 1024). Standalone (R8 put this inside the
// gemm kernel and the gemm hot loop slowed 1.8x -> separated again).
__global__ __launch_bounds__(256) void k_stats(const u8* __restrict__ Xt8,
                                               const float* __restrict__ sp,
                                               const float* __restrict__ dvp,
                                               float* __restrict__ s,
                                               float* __restrict__ dv,
                                               float* __restrict__ xs) {
    __shared__ float sl[DF];
    int sid = blockIdx.x;
    int l = sid >> 2, nc = sid & 3;
    int n0 = nc * 1024;
    int t = threadIdx.x;
    for (int d = t; d < DF; d += 256) {
        float a = 0.f;
#pragma unroll 8
        for (int nt = 0; nt < 64; ++nt) a += sp[((l << 6) + nt) * DF + d];
        sl[d] = a;
        if (nc == 0) s[l * DF + d] = a;
    }
    __syncthreads();
    const u8* xb = Xt8 + (size_t)l * DF * NPTS + n0 + t * 4;
    float a0 = 0, a1 = 0, a2 = 0, a3 = 0;
#pragma unroll 8
    for (int d = 0; d < DF; ++d) {
        unsigned v = *(const unsigned*)(xb + (size_t)d * NPTS);
        float sv = sl[d];
        a0 += sv * __builtin_amdgcn_cvt_f32_fp8(v, 0);
        a1 += sv * __builtin_amdgcn_cvt_f32_fp8(v, 1);
        a2 += sv * __builtin_amdgcn_cvt_f32_fp8(v, 2);
        a3 += sv * __builtin_amdgcn_cvt_f32_fp8(v, 3);
    }
    int n = n0 + t * 4;
    float* xo = xs + l * NPTS + n;
    xo[0] = a0; xo[1] = a1; xo[2] = a2; xo[3] = a3;
#pragma unroll
    for (int j = 0; j < 4; ++j) {
        float dsum = 0.f;
#pragma unroll
        for (int dt2 = 0; dt2 < 8; ++dt2)
            dsum += dvp[((l << 3) + dt2) * NPTS + n + j];
        dv[l * NPTS + n + j] = dsum;
    }
}

// ---------------- K3: fp8 MFMA GEMM (byte-identical to R7) -------------------
// b < 240: diag pair, split-K=4, 128x128 tile, partial C -> CP (exact later).
// else: off-diag pair, split-K=8, 128x256 tile, Frobenius -> atomic F.
// LDS row = 128 B (BK=128 fp8 elems), 8 x 16B groups XOR-swizzled by (row&7).
__global__ __launch_bounds__(256, 2) void k_gemm_frob(const u8* __restrict__ Xt8,
                                                      float* __restrict__ CP,
                                                      float* __restrict__ F) {
    // single shared allocation for BOTH branches (R6 lesson)
    __shared__ __align__(16) u8 As[128 * BKB];             // 16 KB
    __shared__ __align__(16) u8 Bs[256 * BKB];             // 32 KB

    int b = blockIdx.x;
    int t = threadIdx.x, wave = t >> 6, lane = t & 63;
    int rl = lane >> 3, g = lane & 7;          // staging: row-in-8, 16B group
    int row16 = lane & 15, quad = lane >> 4;   // MFMA fragment indices
    int qh = quad >> 1, qb = (quad & 1) * 8;   // frag group-half, byte offset

    if (b < NDIAGBLK) {
        // ---- diag: li, tile tt (10 unique), z in 0..3; 8 iters ----
        int li = b / 40, rem = b % 40, tt = rem >> 2, z = rem & 3;
        int mt = c_TM[tt], nt = c_TN[tt];
        const u8* A = Xt8 + ((size_t)(li * DF + mt * 128)) * NPTS;
        const u8* B = Xt8 + ((size_t)(li * DF + nt * 128)) * NPTS;
        int kLo = z * KCHUNK_D, kHi = kLo + KCHUNK_D;

        int wr = (wave >> 1) * 64, wc = (wave & 1) * 64;
        f32x4 acc[4][4];
#pragma unroll
        for (int mi = 0; mi < 4; ++mi)
#pragma unroll
            for (int ni = 0; ni < 4; ++ni) acc[mi][ni] = (f32x4)0.0f;

        for (int k0 = kLo; k0 < kHi; k0 += BKB) {
            __syncthreads();
#pragma unroll
            for (int is = 0; is < 4; ++is) {               // A,B: 128 rows each
                int rbase = is * 32 + wave * 8;
                int r = rbase + rl;
                int gs = g ^ (r & 7);
                gl2lds16(A + (size_t)r * NPTS + k0 + gs * 16, &As[rbase * BKB]);
                gl2lds16(B + (size_t)r * NPTS + k0 + gs * 16, &Bs[rbase * BKB]);
            }
            __syncthreads();
#pragma unroll
            for (int ko = 0; ko < 4; ++ko) {               // four 32-k steps
                int gi = ko * 2 + qh;
                i64 af[4], bf[4];
#pragma unroll
                for (int mi = 0; mi < 4; ++mi) {
                    int row = wr + mi * 16 + row16;
                    af[mi] = *(const i64*)&As[row * BKB + (gi ^ (row & 7)) * 16 + qb];
                }
#pragma unroll
                for (int ni = 0; ni < 4; ++ni) {
                    int row = wc + ni * 16 + row16;
                    bf[ni] = *(const i64*)&Bs[row * BKB + (gi ^ (row & 7)) * 16 + qb];
                }
#pragma unroll
                for (int mi = 0; mi < 4; ++mi)
#pragma unroll
                    for (int ni = 0; ni < 4; ++ni)
                        acc[mi][ni] = __builtin_amdgcn_mfma_f32_16x16x32_fp8_fp8(
                            af[mi], bf[ni], acc[mi][ni], 0, 0, 0);
            }
        }
        // write partial C tile (lane layout identical across z -> sum aligns)
        float* cp = CP + (((size_t)(li * 10 + tt) * 4 + z) * 16384) + wave * 4096;
#pragma unroll
        for (int mi = 0; mi < 4; ++mi)
#pragma unroll
            for (int ni = 0; ni < 4; ++ni)
#pragma unroll
                for (int e = 0; e < 4; ++e)
                    cp[(mi * 4 + ni) * 256 + e * 64 + lane] = acc[mi][ni][e];
    } else {
        // ---- off-diag: split-K=8, 128x256 tile; 4 iters ----
        int b2 = b - NDIAGBLK;
        int op = b2 >> 6, rem = b2 & 63;
        int tile = rem >> 3, z = rem & 7;
        int pp = c_OFFP[op];
        const u8* A = Xt8 + ((size_t)(c_PI[pp] * DF + (tile & 3) * 128)) * NPTS;
        const u8* B = Xt8 + ((size_t)(c_PJ[pp] * DF + (tile >> 2) * 256)) * NPTS;
        int kLo = z * KCHUNK_O, kHi = kLo + KCHUNK_O;

        int wr = (wave >> 1) * 64, wc = (wave & 1) * 128;
        f32x4 acc[4][8];
#pragma unroll
        for (int mi = 0; mi < 4; ++mi)
#pragma unroll
            for (int ni = 0; ni < 8; ++ni) acc[mi][ni] = (f32x4)0.0f;

        for (int k0 = kLo; k0 < kHi; k0 += BKB) {
            __syncthreads();
#pragma unroll
            for (int is = 0; is < 4; ++is) {               // A: 128 rows
                int rbase = is * 32 + wave * 8;
                int r = rbase + rl;
                int gs = g ^ (r & 7);
                gl2lds16(A + (size_t)r * NPTS + k0 + gs * 16, &As[rbase * BKB]);
            }
#pragma unroll
            for (int is = 0; is < 8; ++is) {               // B: 256 rows
                int rbase = is * 32 + wave * 8;
                int r = rbase + rl;
                int gs = g ^ (r & 7);
                gl2lds16(B + (size_t)r * NPTS + k0 + gs * 16, &Bs[rbase * BKB]);
            }
            __syncthreads();
#pragma unroll
            for (int ko = 0; ko < 4; ++ko) {
                int gi = ko * 2 + qh;
                i64 af[4], bf[8];
#pragma unroll
                for (int mi = 0; mi < 4; ++mi) {
                    int row = wr + mi * 16 + row16;
                    af[mi] = *(const i64*)&As[row * BKB + (gi ^ (row & 7)) * 16 + qb];
                }
#pragma unroll
                for (int ni = 0; ni < 8; ++ni) {
                    int row = wc + ni * 16 + row16;
                    bf[ni] = *(const i64*)&Bs[row * BKB + (gi ^ (row & 7)) * 16 + qb];
                }
#pragma unroll
                for (int mi = 0; mi < 4; ++mi)
#pragma unroll
                    for (int ni = 0; ni < 8; ++ni)
                        acc[mi][ni] = __builtin_amdgcn_mfma_f32_16x16x32_fp8_fp8(
                            af[mi], bf[ni], acc[mi][ni], 0, 0, 0);
            }
        }
        float local = 0.f;
#pragma unroll
        for (int mi = 0; mi < 4; ++mi)
#pragma unroll
            for (int ni = 0; ni < 8; ++ni)
#pragma unroll
                for (int e = 0; e < 4; ++e)
                    local += acc[mi][ni][e] * acc[mi][ni][e];
        for (int off = 32; off; off >>= 1) local += __shfl_down(local, off);
        __shared__ float wsum[4];
        if (lane == 0) wsum[wave] = local;
        __syncthreads();
        if (t == 0) atomicAdd(&F[pp], wsum[0] + wsum[1] + wsum[2] + wsum[3]);
    }
}

// -------- K4: diagred (60) + pairdots (21) + last-block finalize -------------
__global__ __launch_bounds__(256) void k_tail(const float* __restrict__ CP,
                                              const float* __restrict__ dv,
                                              const float* __restrict__ xs,
                                              const float* __restrict__ s,
                                              float* __restrict__ F,
                                              float* __restrict__ ddot,
                                              float* __restrict__ rdot,
                                              float* __restrict__ tb,
                                              unsigned* __restrict__ cnt,
                                              float* __restrict__ out) {
    __shared__ float wsum[4];
    __shared__ float4 red[256];
    __shared__ int lastFlag;
    __shared__ float tbv[ML];
    __shared__ double hs[ML][ML];
    __shared__ float cka[ML][ML];

    int b = blockIdx.x, t = threadIdx.x;

    if (b < 60) {
        // ---- diag reduce: F[ii] += w * sum((sum_z CP_z)^2) ----
        int li = b / 10, tt = b % 10;
        const float* base = CP + (size_t)b * 4 * 16384;
        float a = 0.f;
#pragma unroll 4
        for (int c = 0; c < 64; ++c) {
            int idx = c * 256 + t;
            float v = base[idx] + base[16384 + idx]
                    + base[2 * 16384 + idx] + base[3 * 16384 + idx];
            a += v * v;
        }
        for (int off = 32; off; off >>= 1) a += __shfl_down(a, off);
        if ((t & 63) == 0) wsum[t >> 6] = a;
        __syncthreads();
        if (t == 0) {
            float w = (c_TM[tt] == c_TN[tt]) ? 1.0f : 2.0f;
            atomicAdd(&F[c_DIAGP[li]], w * (wsum[0] + wsum[1] + wsum[2] + wsum[3]));
        }
    } else {
        // ---- pair dots ----
        int p = b - 60, i = c_PI[p], j = c_PJ[p];
        const float invN = 1.0f / (float)NPTS;
        float dd = 0.f, rr = 0.f, sd = 0.f, ss = 0.f;
        for (int n = t; n < NPTS; n += 256) {
            float di = dv[i * NPTS + n], dj = dv[j * NPTS + n];
            float ri = (xs[i * NPTS + n] - di) * invN;
            float rj = (xs[j * NPTS + n] - dj) * invN;
            dd += di * dj;
            rr += ri * rj;
            sd += di;
        }
        for (int c = t; c < DF; c += 256) { float v = s[i * DF + c]; ss += v * v; }
        red[t] = make_float4(dd, rr, sd, ss);
        __syncthreads();
        for (int h = 128; h > 0; h >>= 1) {
            if (t < h) {
                float4 a = red[t], bb = red[t + h];
                red[t] = make_float4(a.x + bb.x, a.y + bb.y, a.z + bb.z, a.w + bb.w);
            }
            __syncthreads();
        }
        if (t == 0) {
            atomicExch(&ddot[p], red[0].x);
            atomicExch(&rdot[p], red[0].y);
            if (i == j)
                atomicExch(&tb[i],
                    (red[0].w - red[0].z) * (1.0f / ((float)NPTS * (float)NPTS)));
        }
    }

    // ---- last-block finalize (atomic counter; no spinning) ----
    __syncthreads();
    if (t == 0) {
        __threadfence();
        unsigned old = atomicAdd(cnt, 1u);
        lastFlag = (old == NTAIL - 1);
    }
    __syncthreads();
    if (!lastFlag) return;
    __threadfence();
    if (t < ML) tbv[t] = atomicAdd(&tb[t], 0.0f);
    __syncthreads();
    if (t < NPAIR) {
        int i = c_PI[t], j = c_PJ[t];
        double Fv = (double)atomicAdd(&F[t], 0.0f);
        double dd = (double)atomicAdd(&ddot[t], 0.0f);
        double rd = (double)atomicAdd(&rdot[t], 0.0f);
        double v = Fv - dd - 2.0 * (double)NPTS * rd
                 + (double)NPTS * (double)NPTS * (double)tbv[i] * (double)tbv[j];
        hs[i][j] = v; hs[j][i] = v;
    }
    __syncthreads();
    if (t < ML * ML) {
        int i = t / ML, j = t % ML;
        float v;
        if (i == j) v = 1.0f;
        else v = (float)(fabs(hs[i][j]) / sqrt(hs[i][i] * hs[j][j] + 1e-6));
        cka[i][j] = v;
        out[t] = v;
    }
    __syncthreads();
    if (t == 0) {
        float l = 0.f;
        for (int i = 1; i < ML; ++i)
            for (int j = 0; j < i; ++j) l += cka[i][j];   // cka >= 0
        out[ML * ML] = l;
    }
}

extern "C" void kernel_launch(void* const* d_in, const int* in_sizes, int n_in,
                              void* d_out, int out_size, void* d_ws, size_t ws_size,
                              hipStream_t stream) {
    (void)in_sizes; (void)n_in; (void)out_size; (void)ws_size;
    const float* X = (const float*)d_in[0];
    float* out = (float*)d_out;
    char* ws = (char*)d_ws;
    u8*    Xt8 = (u8*)(ws + OFF_XT8);
    float* CP  = (float*)(ws + OFF_CP);
    float* sp  = (float*)(ws + OFF_SP);
    float* dvp = (float*)(ws + OFF_DVP);
    float* s   = (float*)(ws + OFF_S);
    float* F   = (float*)(ws + OFF_F);
    unsigned* cnt = (unsigned*)(ws + OFF_F + 256u);
    float* dv  = (float*)(ws + OFF_D);
    float* xs  = (float*)(ws + OFF_XS);
    float* dd  = (float*)(ws + OFF_DD);
    float* rd  = (float*)(ws + OFF_RD);
    float* tb  = (float*)(ws + OFF_T);

    hipLaunchKernelGGL(k_transpose, dim3(64, 8, 6), dim3(256), 0, stream,
                       X, Xt8, sp, dvp, F, cnt);
    hipLaunchKernelGGL(k_stats,     dim3(NSTATS),   dim3(256), 0, stream,
                       Xt8, sp, dvp, s, dv, xs);
    hipLaunchKernelGGL(k_gemm_frob, dim3(NGEMMBLK), dim3(256), 0, stream,
                       Xt8, CP, F);
    hipLaunchKernelGGL(k_tail,      dim3(NTAIL),    dim3(256), 0, stream,
                       CP, dv, xs, s, F, dd, rd, tb, cnt, out);
}

// Round 11
// 133.396 us; speedup vs baseline: 1.3381x; 1.3381x over previous
//
#include <hip/hip_runtime.h>
#include <hip/hip_bf16.h>
#include <stdint.h>

// CKA loss via algebraic reduction:
//   HSIC_ij = ||Xi^T Xj||_F^2 - <d_i,d_j> - 2N<r_i,r_j> + N^2 t_i t_j
// Heavy part: 21 fp8 MFMA GEMMs [512x4096]x[4096x512], Frobenius-reduced.
//
// R11 == R10 with compile fix ('do' is a keyword -> 'dvo').
// R10: R9 exposed k_stats = 53 us (24 blocks, 512 serial strided loads/thread,
// occupancy 0.9% -> latency-bound, no TLP). That also explains R8's "fusion
// regression" (slow stats tail appended to gemm; no contamination). Fix:
// stats 24 -> 192 blocks (8 d-chunks of 64; 64 loads/thread), xs/dv via
// atomicAdd (zeroed by transpose's idle lanes), s[] eliminated (per-chunk
// sp reduction in LDS; sum s^2 -> tbss). Stats re-fused into the gemm grid
// (hidden in its drain tail). 3 dispatches.

#define NPTS  4096
#define DF    512
#define ML    6
#define NPAIR 21
#define BKB   128                // K-bytes per LDS tile row (= 128 fp8 elems)
#define KCHUNK_O 512             // off-diag split-K=8 -> 4 iters
#define KCHUNK_D 1024            // diag split-K=4 -> 8 iters
#define NDIAGBLK 240             // 6 layers x 10 unique tiles x 4 z
#define NOFFBLK  960             // 15 pairs x 8 tiles x 8 z
#define NGEMMBLK (NDIAGBLK + NOFFBLK)
#define NSTATS   192             // 6 layers x 4 n-chunks x 8 d-chunks
#define NTAIL    81              // 60 diagred + 21 pairdots

typedef float  f32x4 __attribute__((ext_vector_type(4)));
typedef unsigned char u8;
typedef long long i64;

__constant__ int c_PI[NPAIR] = {0,0,0,0,0,0, 1,1,1,1,1, 2,2,2,2, 3,3,3, 4,4, 5};
__constant__ int c_PJ[NPAIR] = {0,1,2,3,4,5, 1,2,3,4,5, 2,3,4,5, 3,4,5, 4,5, 5};
__constant__ int c_DIAGP[ML]  = {0, 6, 11, 15, 18, 20};     // p for (i,i)
__constant__ int c_OFFP[15]   = {1,2,3,4,5, 7,8,9,10, 12,13,14, 16,17, 19};
__constant__ int c_TM[10] = {0,0,0,0, 1,1,1, 2,2, 3};       // upper-tri 4x4
__constant__ int c_TN[10] = {0,1,2,3, 1,2,3, 2,3, 3};

// ---- workspace layout (bytes) ----
#define OFF_XT8  0u                       // 6*512*4096   = 12582912
#define OFF_CP   12582912u                // 60*4*64KB    = 15728640
#define OFF_SP   28311552u                // 6*64*512*4   = 786432 (col-sum partials)
#define OFF_DVP  29097984u                // 6*8*4096*4   = 786432 (row-sq partials)
#define OFF_F    29884416u                // 21 floats; cnt at +256; tbss at +512
#define OFF_D    (OFF_F + 1024u)          // 98304 (dv, atomic-accumulated)
#define OFF_XS   (OFF_D + 98304u)         // 98304 (xs, atomic-accumulated)
#define OFF_DD   (OFF_XS + 98304u)
#define OFF_RD   (OFF_DD + 256u)
#define OFF_T    (OFF_RD + 256u)
// total ~30.1 MB

__device__ __forceinline__ unsigned short f2fp8x2(float a, float b) {
    return (unsigned short)(__builtin_amdgcn_cvt_pk_fp8_f32(a, b, 0, false) & 0xffff);
}

__device__ __forceinline__ void gl2lds16(const void* g, void* l) {
    __builtin_amdgcn_global_load_lds(
        (__attribute__((address_space(1))) void*)g,
        (__attribute__((address_space(3))) void*)l, 16, 0, 0);
}

// ------- K1: transpose + fp32->fp8 + partial stats + zero-init ---------------
// X[l][n][d] -> Xt8[l][d][n] (e4m3). sp[(l*64+nt)*512+d] col-sum partial,
// dvp[(l*8+dt)*4096+n] row-sq partial. dt==0 blocks zero dv/xs slices
// (exactly 64+64 floats each: (l*64+nt)*64 spans dv/xs flat). Block 0
// zeroes F, cnt, tbss.
__global__ __launch_bounds__(256) void k_transpose(const float* __restrict__ X,
                                                   u8* __restrict__ Xt8,
                                                   float* __restrict__ sp,
                                                   float* __restrict__ dvp,
                                                   float* __restrict__ F,
                                                   unsigned* __restrict__ cnt,
                                                   float* __restrict__ tbss,
                                                   float* __restrict__ dv,
                                                   float* __restrict__ xs) {
    __shared__ float tT[64][67];
    int nt = blockIdx.x, dt = blockIdx.y, l = blockIdx.z;
    int n0 = nt * 64, d0 = dt * 64;
    int t = threadIdx.x, q = t & 15, r = t >> 4;           // q: d-quad, r: n-row
    if (dt == 0) {
        int zb = (l << 6) + nt;                            // 0..383
        if (t < 64)            dv[zb * 64 + t] = 0.f;
        else if (t < 128)      xs[zb * 64 + (t - 64)] = 0.f;
        if (zb == 0) {
            if (t >= 128 && t < 128 + NPAIR) F[t - 128] = 0.f;
            if (t == 155) *cnt = 0u;
            if (t >= 160 && t < 160 + ML) tbss[t - 160] = 0.f;
        }
    }
    const float4* src = (const float4*)(X + ((size_t)l * NPTS + n0) * DF + d0);
#pragma unroll
    for (int p = 0; p < 4; ++p) {
        int rr = r + 16 * p;
        float4 v = src[(size_t)rr * (DF / 4) + q];
        tT[4 * q + 0][rr] = v.x;
        tT[4 * q + 1][rr] = v.y;
        tT[4 * q + 2][rr] = v.z;
        tT[4 * q + 3][rr] = v.w;
    }
    __syncthreads();
    if (t < 64) {                        // column sums over n (d = t)
        float cs = 0.f;
#pragma unroll
        for (int k = 0; k < 64; ++k) {
            int n = (6 * t + k) & 63;    // rotation -> 2-way banks
            cs += tT[t][n];
        }
        sp[((l << 6) + nt) * DF + d0 + t] = cs;
    } else if (t < 128) {                // row sums of squares over d (n = t-64)
        int n = t - 64;
        float rs = 0.f;
#pragma unroll
        for (int d = 0; d < 64; ++d) { float v = tT[d][n]; rs += v * v; }
        dvp[((l << 3) + dt) * NPTS + n0 + n] = rs;
    }
    // write phase: thread -> (dcol = t>>2, 16 n's) packed as uint4 of fp8
    int dcol = t >> 2, nb = (t & 3) * 16;
    uint4 o;
#pragma unroll
    for (int w2 = 0; w2 < 4; ++w2) {
        int j = nb + w2 * 4;
        unsigned lo = f2fp8x2(tT[dcol][j + 0], tT[dcol][j + 1]);
        unsigned hi = f2fp8x2(tT[dcol][j + 2], tT[dcol][j + 3]);
        ((unsigned*)&o)[w2] = lo | (hi << 16);
    }
    *(uint4*)(Xt8 + ((size_t)(l * DF + d0 + dcol)) * NPTS + n0 + nb) = o;
}

// ---------------- K2: fp8 MFMA GEMM + parallel stats blocks ------------------
// b < 240: diag pair, split-K=4, 128x128 tile, partial C -> CP (exact later).
// b < 1200: off-diag pair, split-K=8, 128x256 tile, Frobenius -> atomic F.
// b >= 1200: stats (l, n-chunk of 1024, d-chunk of 64): 64 loads/thread,
//            atomicAdd into xs/dv; nc==0 blocks add sum(s^2) chunk to tbss.
__global__ __launch_bounds__(256, 2) void k_gemm_frob(const u8* __restrict__ Xt8,
                                                      float* __restrict__ CP,
                                                      float* __restrict__ F,
                                                      const float* __restrict__ sp,
                                                      const float* __restrict__ dvp,
                                                      float* __restrict__ dv,
                                                      float* __restrict__ xs,
                                                      float* __restrict__ tbss) {
    // single shared allocation for ALL branches (R6 lesson)
    __shared__ __align__(16) u8 As[128 * BKB];             // 16 KB
    __shared__ __align__(16) u8 Bs[256 * BKB];             // 32 KB

    int b = blockIdx.x;
    int t = threadIdx.x, wave = t >> 6, lane = t & 63;
    int rl = lane >> 3, g = lane & 7;          // staging: row-in-8, 16B group
    int row16 = lane & 15, quad = lane >> 4;   // MFMA fragment indices
    int qh = quad >> 1, qb = (quad & 1) * 8;   // frag group-half, byte offset

    if (b < NDIAGBLK) {
        // ---- diag: li, tile tt (10 unique), z in 0..3; 8 iters ----
        int li = b / 40, rem = b % 40, tt = rem >> 2, z = rem & 3;
        int mt = c_TM[tt], nt = c_TN[tt];
        const u8* A = Xt8 + ((size_t)(li * DF + mt * 128)) * NPTS;
        const u8* B = Xt8 + ((size_t)(li * DF + nt * 128)) * NPTS;
        int kLo = z * KCHUNK_D, kHi = kLo + KCHUNK_D;

        int wr = (wave >> 1) * 64, wc = (wave & 1) * 64;
        f32x4 acc[4][4];
#pragma unroll
        for (int mi = 0; mi < 4; ++mi)
#pragma unroll
            for (int ni = 0; ni < 4; ++ni) acc[mi][ni] = (f32x4)0.0f;

        for (int k0 = kLo; k0 < kHi; k0 += BKB) {
            __syncthreads();
#pragma unroll
            for (int is = 0; is < 4; ++is) {               // A,B: 128 rows each
                int rbase = is * 32 + wave * 8;
                int r = rbase + rl;
                int gs = g ^ (r & 7);
                gl2lds16(A + (size_t)r * NPTS + k0 + gs * 16, &As[rbase * BKB]);
                gl2lds16(B + (size_t)r * NPTS + k0 + gs * 16, &Bs[rbase * BKB]);
            }
            __syncthreads();
#pragma unroll
            for (int ko = 0; ko < 4; ++ko) {               // four 32-k steps
                int gi = ko * 2 + qh;
                i64 af[4], bf[4];
#pragma unroll
                for (int mi = 0; mi < 4; ++mi) {
                    int row = wr + mi * 16 + row16;
                    af[mi] = *(const i64*)&As[row * BKB + (gi ^ (row & 7)) * 16 + qb];
                }
#pragma unroll
                for (int ni = 0; ni < 4; ++ni) {
                    int row = wc + ni * 16 + row16;
                    bf[ni] = *(const i64*)&Bs[row * BKB + (gi ^ (row & 7)) * 16 + qb];
                }
#pragma unroll
                for (int mi = 0; mi < 4; ++mi)
#pragma unroll
                    for (int ni = 0; ni < 4; ++ni)
                        acc[mi][ni] = __builtin_amdgcn_mfma_f32_16x16x32_fp8_fp8(
                            af[mi], bf[ni], acc[mi][ni], 0, 0, 0);
            }
        }
        // write partial C tile (lane layout identical across z -> sum aligns)
        float* cp = CP + (((size_t)(li * 10 + tt) * 4 + z) * 16384) + wave * 4096;
#pragma unroll
        for (int mi = 0; mi < 4; ++mi)
#pragma unroll
            for (int ni = 0; ni < 4; ++ni)
#pragma unroll
                for (int e = 0; e < 4; ++e)
                    cp[(mi * 4 + ni) * 256 + e * 64 + lane] = acc[mi][ni][e];
    } else if (b < NGEMMBLK) {
        // ---- off-diag: split-K=8, 128x256 tile; 4 iters ----
        int b2 = b - NDIAGBLK;
        int op = b2 >> 6, rem = b2 & 63;
        int tile = rem >> 3, z = rem & 7;
        int pp = c_OFFP[op];
        const u8* A = Xt8 + ((size_t)(c_PI[pp] * DF + (tile & 3) * 128)) * NPTS;
        const u8* B = Xt8 + ((size_t)(c_PJ[pp] * DF + (tile >> 2) * 256)) * NPTS;
        int kLo = z * KCHUNK_O, kHi = kLo + KCHUNK_O;

        int wr = (wave >> 1) * 64, wc = (wave & 1) * 128;
        f32x4 acc[4][8];
#pragma unroll
        for (int mi = 0; mi < 4; ++mi)
#pragma unroll
            for (int ni = 0; ni < 8; ++ni) acc[mi][ni] = (f32x4)0.0f;

        for (int k0 = kLo; k0 < kHi; k0 += BKB) {
            __syncthreads();
#pragma unroll
            for (int is = 0; is < 4; ++is) {               // A: 128 rows
                int rbase = is * 32 + wave * 8;
                int r = rbase + rl;
                int gs = g ^ (r & 7);
                gl2lds16(A + (size_t)r * NPTS + k0 + gs * 16, &As[rbase * BKB]);
            }
#pragma unroll
            for (int is = 0; is < 8; ++is) {               // B: 256 rows
                int rbase = is * 32 + wave * 8;
                int r = rbase + rl;
                int gs = g ^ (r & 7);
                gl2lds16(B + (size_t)r * NPTS + k0 + gs * 16, &Bs[rbase * BKB]);
            }
            __syncthreads();
#pragma unroll
            for (int ko = 0; ko < 4; ++ko) {
                int gi = ko * 2 + qh;
                i64 af[4], bf[8];
#pragma unroll
                for (int mi = 0; mi < 4; ++mi) {
                    int row = wr + mi * 16 + row16;
                    af[mi] = *(const i64*)&As[row * BKB + (gi ^ (row & 7)) * 16 + qb];
                }
#pragma unroll
                for (int ni = 0; ni < 8; ++ni) {
                    int row = wc + ni * 16 + row16;
                    bf[ni] = *(const i64*)&Bs[row * BKB + (gi ^ (row & 7)) * 16 + qb];
                }
#pragma unroll
                for (int mi = 0; mi < 4; ++mi)
#pragma unroll
                    for (int ni = 0; ni < 8; ++ni)
                        acc[mi][ni] = __builtin_amdgcn_mfma_f32_16x16x32_fp8_fp8(
                            af[mi], bf[ni], acc[mi][ni], 0, 0, 0);
            }
        }
        float local = 0.f;
#pragma unroll
        for (int mi = 0; mi < 4; ++mi)
#pragma unroll
            for (int ni = 0; ni < 8; ++ni)
#pragma unroll
                for (int e = 0; e < 4; ++e)
                    local += acc[mi][ni][e] * acc[mi][ni][e];
        for (int off = 32; off; off >>= 1) local += __shfl_down(local, off);
        __shared__ float wsum[4];
        if (lane == 0) wsum[wave] = local;
        __syncthreads();
        if (t == 0) atomicAdd(&F[pp], wsum[0] + wsum[1] + wsum[2] + wsum[3]);
    } else {
        // ---- stats: sid -> (l, dc, nc). 64 loads/thread. ----
        int sid = b - NGEMMBLK;
        int l = sid >> 5, rem = sid & 31, dc = rem >> 2, nc = rem & 3;
        int d0 = dc * 64, n0 = nc * 1024;
        float* scratch = (float*)As;                       // 256 floats
        float* slp = (float*)As + 256;                     // 64 floats

        // reduce sp -> s values for this 64-d chunk (into LDS)
        int dl = t & 63, part = t >> 6;
        float a = 0.f;
#pragma unroll 4
        for (int k = 0; k < 16; ++k)
            a += sp[((l << 6) + part * 16 + k) * DF + d0 + dl];
        scratch[t] = a;
        __syncthreads();
        if (t < 64)
            slp[t] = scratch[t] + scratch[64 + t] + scratch[128 + t] + scratch[192 + t];
        __syncthreads();
        if (nc == 0 && t == 0) {                           // sum s^2 chunk
            float q2 = 0.f;
#pragma unroll
            for (int d = 0; d < 64; ++d) q2 += slp[d] * slp[d];
            atomicAdd(&tbss[l], q2);
        }
        // xs partial: 64 strided loads, 4 n's per thread
        int n = n0 + t * 4;
        const u8* xb = Xt8 + (size_t)(l * DF + d0) * NPTS + n;
        float a0 = 0, a1 = 0, a2 = 0, a3 = 0;
#pragma unroll 8
        for (int dd = 0; dd < 64; ++dd) {
            unsigned v = *(const unsigned*)(xb + (size_t)dd * NPTS);
            float sv = slp[dd];
            a0 += sv * __builtin_amdgcn_cvt_f32_fp8(v, 0);
            a1 += sv * __builtin_amdgcn_cvt_f32_fp8(v, 1);
            a2 += sv * __builtin_amdgcn_cvt_f32_fp8(v, 2);
            a3 += sv * __builtin_amdgcn_cvt_f32_fp8(v, 3);
        }
        float* xo = xs + l * NPTS + n;
        atomicAdd(&xo[0], a0); atomicAdd(&xo[1], a1);
        atomicAdd(&xo[2], a2); atomicAdd(&xo[3], a3);
        // dv partial: this block owns dvp chunk dc for its n's
        float4 dp = *(const float4*)(dvp + ((l << 3) + dc) * NPTS + n);
        float* dvo = dv + l * NPTS + n;
        atomicAdd(&dvo[0], dp.x); atomicAdd(&dvo[1], dp.y);
        atomicAdd(&dvo[2], dp.z); atomicAdd(&dvo[3], dp.w);
    }
}

// -------- K3: diagred (60) + pairdots (21) + last-block finalize -------------
__global__ __launch_bounds__(256) void k_tail(const float* __restrict__ CP,
                                              const float* __restrict__ dv,
                                              const float* __restrict__ xs,
                                              const float* __restrict__ tbss,
                                              float* __restrict__ F,
                                              float* __restrict__ ddot,
                                              float* __restrict__ rdot,
                                              float* __restrict__ tb,
                                              unsigned* __restrict__ cnt,
                                              float* __restrict__ out) {
    __shared__ float wsum[4];
    __shared__ float4 red[256];
    __shared__ int lastFlag;
    __shared__ float tbv[ML];
    __shared__ double hs[ML][ML];
    __shared__ float cka[ML][ML];

    int b = blockIdx.x, t = threadIdx.x;

    if (b < 60) {
        // ---- diag reduce: F[ii] += w * sum((sum_z CP_z)^2) ----
        int li = b / 10, tt = b % 10;
        const float* base = CP + (size_t)b * 4 * 16384;
        float a = 0.f;
#pragma unroll 4
        for (int c = 0; c < 64; ++c) {
            int idx = c * 256 + t;
            float v = base[idx] + base[16384 + idx]
                    + base[2 * 16384 + idx] + base[3 * 16384 + idx];
            a += v * v;
        }
        for (int off = 32; off; off >>= 1) a += __shfl_down(a, off);
        if ((t & 63) == 0) wsum[t >> 6] = a;
        __syncthreads();
        if (t == 0) {
            float w = (c_TM[tt] == c_TN[tt]) ? 1.0f : 2.0f;
            atomicAdd(&F[c_DIAGP[li]], w * (wsum[0] + wsum[1] + wsum[2] + wsum[3]));
        }
    } else {
        // ---- pair dots ----
        int p = b - 60, i = c_PI[p], j = c_PJ[p];
        const float invN = 1.0f / (float)NPTS;
        float dd = 0.f, rr = 0.f, sd = 0.f;
        for (int n = t; n < NPTS; n += 256) {
            float di = dv[i * NPTS + n], dj = dv[j * NPTS + n];
            float ri = (xs[i * NPTS + n] - di) * invN;
            float rj = (xs[j * NPTS + n] - dj) * invN;
            dd += di * dj;
            rr += ri * rj;
            sd += di;
        }
        red[t] = make_float4(dd, rr, sd, 0.f);
        __syncthreads();
        for (int h = 128; h > 0; h >>= 1) {
            if (t < h) {
                float4 a = red[t], bb = red[t + h];
                red[t] = make_float4(a.x + bb.x, a.y + bb.y, a.z + bb.z, 0.f);
            }
            __syncthreads();
        }
        if (t == 0) {
            atomicExch(&ddot[p], red[0].x);
            atomicExch(&rdot[p], red[0].y);
            if (i == j)
                atomicExch(&tb[i],
                    (tbss[i] - red[0].z) * (1.0f / ((float)NPTS * (float)NPTS)));
        }
    }

    // ---- last-block finalize (atomic counter; no spinning) ----
    __syncthreads();
    if (t == 0) {
        __threadfence();
        unsigned old = atomicAdd(cnt, 1u);
        lastFlag = (old == NTAIL - 1);
    }
    __syncthreads();
    if (!lastFlag) return;
    __threadfence();
    if (t < ML) tbv[t] = atomicAdd(&tb[t], 0.0f);
    __syncthreads();
    if (t < NPAIR) {
        int i = c_PI[t], j = c_PJ[t];
        double Fv = (double)atomicAdd(&F[t], 0.0f);
        double dd = (double)atomicAdd(&ddot[t], 0.0f);
        double rd = (double)atomicAdd(&rdot[t], 0.0f);
        double v = Fv - dd - 2.0 * (double)NPTS * rd
                 + (double)NPTS * (double)NPTS * (double)tbv[i] * (double)tbv[j];
        hs[i][j] = v; hs[j][i] = v;
    }
    __syncthreads();
    if (t < ML * ML) {
        int i = t / ML, j = t % ML;
        float v;
        if (i == j) v = 1.0f;
        else v = (float)(fabs(hs[i][j]) / sqrt(hs[i][i] * hs[j][j] + 1e-6));
        cka[i][j] = v;
        out[t] = v;
    }
    __syncthreads();
    if (t == 0) {
        float l = 0.f;
        for (int i = 1; i < ML; ++i)
            for (int j = 0; j < i; ++j) l += cka[i][j];   // cka >= 0
        out[ML * ML] = l;
    }
}

extern "C" void kernel_launch(void* const* d_in, const int* in_sizes, int n_in,
                              void* d_out, int out_size, void* d_ws, size_t ws_size,
                              hipStream_t stream) {
    (void)in_sizes; (void)n_in; (void)out_size; (void)ws_size;
    const float* X = (const float*)d_in[0];
    float* out = (float*)d_out;
    char* ws = (char*)d_ws;
    u8*    Xt8 = (u8*)(ws + OFF_XT8);
    float* CP  = (float*)(ws + OFF_CP);
    float* sp  = (float*)(ws + OFF_SP);
    float* dvp = (float*)(ws + OFF_DVP);
    float* F   = (float*)(ws + OFF_F);
    unsigned* cnt = (unsigned*)(ws + OFF_F + 256u);
    float* tbss = (float*)(ws + OFF_F + 512u);
    float* dv  = (float*)(ws + OFF_D);
    float* xs  = (float*)(ws + OFF_XS);
    float* dd  = (float*)(ws + OFF_DD);
    float* rd  = (float*)(ws + OFF_RD);
    float* tb  = (float*)(ws + OFF_T);

    hipLaunchKernelGGL(k_transpose, dim3(64, 8, 6), dim3(256), 0, stream,
                       X, Xt8, sp, dvp, F, cnt, tbss, dv, xs);
    hipLaunchKernelGGL(k_gemm_frob, dim3(NGEMMBLK + NSTATS), dim3(256), 0, stream,
                       Xt8, CP, F, sp, dvp, dv, xs, tbss);
    hipLaunchKernelGGL(k_tail, dim3(NTAIL), dim3(256), 0, stream,
                       CP, dv, xs, tbss, F, dd, rd, tb, cnt, out);
}

// Round 12
// 127.822 us; speedup vs baseline: 1.3965x; 1.0436x over previous
//
#include <hip/hip_runtime.h>
#include <hip/hip_bf16.h>
#include <stdint.h>

// CKA loss via algebraic reduction:
//   HSIC_ij = ||Xi^T Xj||_F^2 - <d_i,d_j> - 2N<r_i,r_j> + N^2 t_i t_j
// Heavy part: 21 fp8 MFMA GEMMs [512x4096]x[4096x512], Frobenius-reduced.
//
// R12: gemm switched to MX-scaled fp8 (mfma_scale_f32_16x16x128_f8f6f4,
// unit e8m0 scales = 127): 2x MFMA rate (m148: 995->1628 TF on the same
// 128-tile structure), and 32B/lane fragments -> pure ds_read_b128
// (eliminates the structural 4-way b64 conflict, 3.9M cyc in R11).
// With uniform scales any A/B-shared k-permutation cancels in the dot
// product and C/D layout is Frobenius-invariant -> layout-bug-immune.
// Everything outside the MFMA inner loops is identical to R11 (133.4 us,
// gemm dispatch 44.0, stats blocks fully hidden).

#define NPTS  4096
#define DF    512
#define ML    6
#define NPAIR 21
#define BKB   128                // K-bytes per LDS tile row (= 128 fp8 elems)
#define KCHUNK_O 512             // off-diag split-K=8 -> 4 iters
#define KCHUNK_D 1024            // diag split-K=4 -> 8 iters
#define NDIAGBLK 240             // 6 layers x 10 unique tiles x 4 z
#define NOFFBLK  960             // 15 pairs x 8 tiles x 8 z
#define NGEMMBLK (NDIAGBLK + NOFFBLK)
#define NSTATS   192             // 6 layers x 4 n-chunks x 8 d-chunks
#define NTAIL    81              // 60 diagred + 21 pairdots

typedef float  f32x4 __attribute__((ext_vector_type(4)));
typedef int    i32x4v __attribute__((ext_vector_type(4)));
typedef int    i32x8v __attribute__((ext_vector_type(8)));
typedef unsigned char u8;

__constant__ int c_PI[NPAIR] = {0,0,0,0,0,0, 1,1,1,1,1, 2,2,2,2, 3,3,3, 4,4, 5};
__constant__ int c_PJ[NPAIR] = {0,1,2,3,4,5, 1,2,3,4,5, 2,3,4,5, 3,4,5, 4,5, 5};
__constant__ int c_DIAGP[ML]  = {0, 6, 11, 15, 18, 20};     // p for (i,i)
__constant__ int c_OFFP[15]   = {1,2,3,4,5, 7,8,9,10, 12,13,14, 16,17, 19};
__constant__ int c_TM[10] = {0,0,0,0, 1,1,1, 2,2, 3};       // upper-tri 4x4
__constant__ int c_TN[10] = {0,1,2,3, 1,2,3, 2,3, 3};

// ---- workspace layout (bytes) ----
#define OFF_XT8  0u                       // 6*512*4096   = 12582912
#define OFF_CP   12582912u                // 60*4*64KB    = 15728640
#define OFF_SP   28311552u                // 6*64*512*4   = 786432 (col-sum partials)
#define OFF_DVP  29097984u                // 6*8*4096*4   = 786432 (row-sq partials)
#define OFF_F    29884416u                // 21 floats; cnt at +256; tbss at +512
#define OFF_D    (OFF_F + 1024u)          // 98304 (dv, atomic-accumulated)
#define OFF_XS   (OFF_D + 98304u)         // 98304 (xs, atomic-accumulated)
#define OFF_DD   (OFF_XS + 98304u)
#define OFF_RD   (OFF_DD + 256u)
#define OFF_T    (OFF_RD + 256u)
// total ~30.1 MB

#define UNIT_SCALE 127                    // e8m0: 2^(127-127) = 1.0

__device__ __forceinline__ unsigned short f2fp8x2(float a, float b) {
    return (unsigned short)(__builtin_amdgcn_cvt_pk_fp8_f32(a, b, 0, false) & 0xffff);
}

__device__ __forceinline__ void gl2lds16(const void* g, void* l) {
    __builtin_amdgcn_global_load_lds(
        (__attribute__((address_space(1))) void*)g,
        (__attribute__((address_space(3))) void*)l, 16, 0, 0);
}

// load one 32B MX fragment (k-block = quad*32..+31) from a swizzled LDS row
__device__ __forceinline__ i32x8v frag32(const u8* base, int row, int quad) {
    int sw = row & 7;
    i32x4v lo = *(const i32x4v*)&base[row * BKB + ((2 * quad) ^ sw) * 16];
    i32x4v hi = *(const i32x4v*)&base[row * BKB + ((2 * quad + 1) ^ sw) * 16];
    return __builtin_shufflevector(lo, hi, 0, 1, 2, 3, 4, 5, 6, 7);
}

// ------- K1: transpose + fp32->fp8 + partial stats + zero-init ---------------
__global__ __launch_bounds__(256) void k_transpose(const float* __restrict__ X,
                                                   u8* __restrict__ Xt8,
                                                   float* __restrict__ sp,
                                                   float* __restrict__ dvp,
                                                   float* __restrict__ F,
                                                   unsigned* __restrict__ cnt,
                                                   float* __restrict__ tbss,
                                                   float* __restrict__ dv,
                                                   float* __restrict__ xs) {
    __shared__ float tT[64][67];
    int nt = blockIdx.x, dt = blockIdx.y, l = blockIdx.z;
    int n0 = nt * 64, d0 = dt * 64;
    int t = threadIdx.x, q = t & 15, r = t >> 4;           // q: d-quad, r: n-row
    if (dt == 0) {
        int zb = (l << 6) + nt;                            // 0..383
        if (t < 64)            dv[zb * 64 + t] = 0.f;
        else if (t < 128)      xs[zb * 64 + (t - 64)] = 0.f;
        if (zb == 0) {
            if (t >= 128 && t < 128 + NPAIR) F[t - 128] = 0.f;
            if (t == 155) *cnt = 0u;
            if (t >= 160 && t < 160 + ML) tbss[t - 160] = 0.f;
        }
    }
    const float4* src = (const float4*)(X + ((size_t)l * NPTS + n0) * DF + d0);
#pragma unroll
    for (int p = 0; p < 4; ++p) {
        int rr = r + 16 * p;
        float4 v = src[(size_t)rr * (DF / 4) + q];
        tT[4 * q + 0][rr] = v.x;
        tT[4 * q + 1][rr] = v.y;
        tT[4 * q + 2][rr] = v.z;
        tT[4 * q + 3][rr] = v.w;
    }
    __syncthreads();
    if (t < 64) {                        // column sums over n (d = t)
        float cs = 0.f;
#pragma unroll
        for (int k = 0; k < 64; ++k) {
            int n = (6 * t + k) & 63;    // rotation -> 2-way banks
            cs += tT[t][n];
        }
        sp[((l << 6) + nt) * DF + d0 + t] = cs;
    } else if (t < 128) {                // row sums of squares over d (n = t-64)
        int n = t - 64;
        float rs = 0.f;
#pragma unroll
        for (int d = 0; d < 64; ++d) { float v = tT[d][n]; rs += v * v; }
        dvp[((l << 3) + dt) * NPTS + n0 + n] = rs;
    }
    // write phase: thread -> (dcol = t>>2, 16 n's) packed as uint4 of fp8
    int dcol = t >> 2, nb = (t & 3) * 16;
    uint4 o;
#pragma unroll
    for (int w2 = 0; w2 < 4; ++w2) {
        int j = nb + w2 * 4;
        unsigned lo = f2fp8x2(tT[dcol][j + 0], tT[dcol][j + 1]);
        unsigned hi = f2fp8x2(tT[dcol][j + 2], tT[dcol][j + 3]);
        ((unsigned*)&o)[w2] = lo | (hi << 16);
    }
    *(uint4*)(Xt8 + ((size_t)(l * DF + d0 + dcol)) * NPTS + n0 + nb) = o;
}

// ---------------- K2: MX-fp8 MFMA GEMM + parallel stats blocks ---------------
// b < 240: diag pair, split-K=4, 128x128 tile, partial C -> CP (exact later).
// b < 1200: off-diag pair, split-K=8, 128x256 tile, Frobenius -> atomic F.
// b >= 1200: stats (l, n-chunk, d-chunk): atomicAdd into xs/dv; tbss.
__global__ __launch_bounds__(256, 2) void k_gemm_frob(const u8* __restrict__ Xt8,
                                                      float* __restrict__ CP,
                                                      float* __restrict__ F,
                                                      const float* __restrict__ sp,
                                                      const float* __restrict__ dvp,
                                                      float* __restrict__ dv,
                                                      float* __restrict__ xs,
                                                      float* __restrict__ tbss) {
    // single shared allocation for ALL branches (R6 lesson)
    __shared__ __align__(16) u8 As[128 * BKB];             // 16 KB
    __shared__ __align__(16) u8 Bs[256 * BKB];             // 32 KB

    int b = blockIdx.x;
    int t = threadIdx.x, wave = t >> 6, lane = t & 63;
    int rl = lane >> 3, g = lane & 7;          // staging: row-in-8, 16B group
    int row16 = lane & 15, quad = lane >> 4;   // MFMA fragment indices

    if (b < NDIAGBLK) {
        // ---- diag: li, tile tt (10 unique), z in 0..3; 8 iters ----
        int li = b / 40, rem = b % 40, tt = rem >> 2, z = rem & 3;
        int mt = c_TM[tt], nt = c_TN[tt];
        const u8* A = Xt8 + ((size_t)(li * DF + mt * 128)) * NPTS;
        const u8* B = Xt8 + ((size_t)(li * DF + nt * 128)) * NPTS;
        int kLo = z * KCHUNK_D, kHi = kLo + KCHUNK_D;

        int wr = (wave >> 1) * 64, wc = (wave & 1) * 64;
        f32x4 acc[4][4];
#pragma unroll
        for (int mi = 0; mi < 4; ++mi)
#pragma unroll
            for (int ni = 0; ni < 4; ++ni) acc[mi][ni] = (f32x4)0.0f;

        for (int k0 = kLo; k0 < kHi; k0 += BKB) {
            __syncthreads();
#pragma unroll
            for (int is = 0; is < 4; ++is) {               // A,B: 128 rows each
                int rbase = is * 32 + wave * 8;
                int r = rbase + rl;
                int gs = g ^ (r & 7);
                gl2lds16(A + (size_t)r * NPTS + k0 + gs * 16, &As[rbase * BKB]);
                gl2lds16(B + (size_t)r * NPTS + k0 + gs * 16, &Bs[rbase * BKB]);
            }
            __syncthreads();
            i32x8v af[4];
#pragma unroll
            for (int mi = 0; mi < 4; ++mi)
                af[mi] = frag32(As, wr + mi * 16 + row16, quad);
#pragma unroll
            for (int ni = 0; ni < 4; ++ni) {
                i32x8v bf = frag32(Bs, wc + ni * 16 + row16, quad);
#pragma unroll
                for (int mi = 0; mi < 4; ++mi)
                    acc[mi][ni] = __builtin_amdgcn_mfma_scale_f32_16x16x128_f8f6f4(
                        af[mi], bf, acc[mi][ni], 0, 0,
                        0, UNIT_SCALE, 0, UNIT_SCALE);
            }
        }
        // write partial C tile (lane layout identical across z -> sum aligns)
        float* cp = CP + (((size_t)(li * 10 + tt) * 4 + z) * 16384) + wave * 4096;
#pragma unroll
        for (int mi = 0; mi < 4; ++mi)
#pragma unroll
            for (int ni = 0; ni < 4; ++ni)
#pragma unroll
                for (int e = 0; e < 4; ++e)
                    cp[(mi * 4 + ni) * 256 + e * 64 + lane] = acc[mi][ni][e];
    } else if (b < NGEMMBLK) {
        // ---- off-diag: split-K=8, 128x256 tile; 4 iters ----
        int b2 = b - NDIAGBLK;
        int op = b2 >> 6, rem = b2 & 63;
        int tile = rem >> 3, z = rem & 7;
        int pp = c_OFFP[op];
        const u8* A = Xt8 + ((size_t)(c_PI[pp] * DF + (tile & 3) * 128)) * NPTS;
        const u8* B = Xt8 + ((size_t)(c_PJ[pp] * DF + (tile >> 2) * 256)) * NPTS;
        int kLo = z * KCHUNK_O, kHi = kLo + KCHUNK_O;

        int wr = (wave >> 1) * 64, wc = (wave & 1) * 128;
        f32x4 acc[4][8];
#pragma unroll
        for (int mi = 0; mi < 4; ++mi)
#pragma unroll
            for (int ni = 0; ni < 8; ++ni) acc[mi][ni] = (f32x4)0.0f;

        for (int k0 = kLo; k0 < kHi; k0 += BKB) {
            __syncthreads();
#pragma unroll
            for (int is = 0; is < 4; ++is) {               // A: 128 rows
                int rbase = is * 32 + wave * 8;
                int r = rbase + rl;
                int gs = g ^ (r & 7);
                gl2lds16(A + (size_t)r * NPTS + k0 + gs * 16, &As[rbase * BKB]);
            }
#pragma unroll
            for (int is = 0; is < 8; ++is) {               // B: 256 rows
                int rbase = is * 32 + wave * 8;
                int r = rbase + rl;
                int gs = g ^ (r & 7);
                gl2lds16(B + (size_t)r * NPTS + k0 + gs * 16, &Bs[rbase * BKB]);
            }
            __syncthreads();
            i32x8v af[4];
#pragma unroll
            for (int mi = 0; mi < 4; ++mi)
                af[mi] = frag32(As, wr + mi * 16 + row16, quad);
#pragma unroll
            for (int ni = 0; ni < 8; ++ni) {
                i32x8v bf = frag32(Bs, wc + ni * 16 + row16, quad);
#pragma unroll
                for (int mi = 0; mi < 4; ++mi)
                    acc[mi][ni] = __builtin_amdgcn_mfma_scale_f32_16x16x128_f8f6f4(
                        af[mi], bf, acc[mi][ni], 0, 0,
                        0, UNIT_SCALE, 0, UNIT_SCALE);
            }
        }
        float local = 0.f;
#pragma unroll
        for (int mi = 0; mi < 4; ++mi)
#pragma unroll
            for (int ni = 0; ni < 8; ++ni)
#pragma unroll
                for (int e = 0; e < 4; ++e)
                    local += acc[mi][ni][e] * acc[mi][ni][e];
        for (int off = 32; off; off >>= 1) local += __shfl_down(local, off);
        __shared__ float wsum[4];
        if (lane == 0) wsum[wave] = local;
        __syncthreads();
        if (t == 0) atomicAdd(&F[pp], wsum[0] + wsum[1] + wsum[2] + wsum[3]);
    } else {
        // ---- stats: sid -> (l, dc, nc). 64 loads/thread. ----
        int sid = b - NGEMMBLK;
        int l = sid >> 5, rem = sid & 31, dc = rem >> 2, nc = rem & 3;
        int d0 = dc * 64, n0 = nc * 1024;
        float* scratch = (float*)As;                       // 256 floats
        float* slp = (float*)As + 256;                     // 64 floats

        // reduce sp -> s values for this 64-d chunk (into LDS)
        int dl = t & 63, part = t >> 6;
        float a = 0.f;
#pragma unroll 4
        for (int k = 0; k < 16; ++k)
            a += sp[((l << 6) + part * 16 + k) * DF + d0 + dl];
        scratch[t] = a;
        __syncthreads();
        if (t < 64)
            slp[t] = scratch[t] + scratch[64 + t] + scratch[128 + t] + scratch[192 + t];
        __syncthreads();
        if (nc == 0 && t == 0) {                           // sum s^2 chunk
            float q2 = 0.f;
#pragma unroll
            for (int d = 0; d < 64; ++d) q2 += slp[d] * slp[d];
            atomicAdd(&tbss[l], q2);
        }
        // xs partial: 64 strided loads, 4 n's per thread
        int n = n0 + t * 4;
        const u8* xb = Xt8 + (size_t)(l * DF + d0) * NPTS + n;
        float a0 = 0, a1 = 0, a2 = 0, a3 = 0;
#pragma unroll 8
        for (int dd = 0; dd < 64; ++dd) {
            unsigned v = *(const unsigned*)(xb + (size_t)dd * NPTS);
            float sv = slp[dd];
            a0 += sv * __builtin_amdgcn_cvt_f32_fp8(v, 0);
            a1 += sv * __builtin_amdgcn_cvt_f32_fp8(v, 1);
            a2 += sv * __builtin_amdgcn_cvt_f32_fp8(v, 2);
            a3 += sv * __builtin_amdgcn_cvt_f32_fp8(v, 3);
        }
        float* xo = xs + l * NPTS + n;
        atomicAdd(&xo[0], a0); atomicAdd(&xo[1], a1);
        atomicAdd(&xo[2], a2); atomicAdd(&xo[3], a3);
        // dv partial: this block owns dvp chunk dc for its n's
        float4 dp = *(const float4*)(dvp + ((l << 3) + dc) * NPTS + n);
        float* dvo = dv + l * NPTS + n;
        atomicAdd(&dvo[0], dp.x); atomicAdd(&dvo[1], dp.y);
        atomicAdd(&dvo[2], dp.z); atomicAdd(&dvo[3], dp.w);
    }
}

// -------- K3: diagred (60) + pairdots (21) + last-block finalize -------------
__global__ __launch_bounds__(256) void k_tail(const float* __restrict__ CP,
                                              const float* __restrict__ dv,
                                              const float* __restrict__ xs,
                                              const float* __restrict__ tbss,
                                              float* __restrict__ F,
                                              float* __restrict__ ddot,
                                              float* __restrict__ rdot,
                                              float* __restrict__ tb,
                                              unsigned* __restrict__ cnt,
                                              float* __restrict__ out) {
    __shared__ float wsum[4];
    __shared__ float4 red[256];
    __shared__ int lastFlag;
    __shared__ float tbv[ML];
    __shared__ double hs[ML][ML];
    __shared__ float cka[ML][ML];

    int b = blockIdx.x, t = threadIdx.x;

    if (b < 60) {
        // ---- diag reduce: F[ii] += w * sum((sum_z CP_z)^2) ----
        int li = b / 10, tt = b % 10;
        const float* base = CP + (size_t)b * 4 * 16384;
        float a = 0.f;
#pragma unroll 4
        for (int c = 0; c < 64; ++c) {
            int idx = c * 256 + t;
            float v = base[idx] + base[16384 + idx]
                    + base[2 * 16384 + idx] + base[3 * 16384 + idx];
            a += v * v;
        }
        for (int off = 32; off; off >>= 1) a += __shfl_down(a, off);
        if ((t & 63) == 0) wsum[t >> 6] = a;
        __syncthreads();
        if (t == 0) {
            float w = (c_TM[tt] == c_TN[tt]) ? 1.0f : 2.0f;
            atomicAdd(&F[c_DIAGP[li]], w * (wsum[0] + wsum[1] + wsum[2] + wsum[3]));
        }
    } else {
        // ---- pair dots ----
        int p = b - 60, i = c_PI[p], j = c_PJ[p];
        const float invN = 1.0f / (float)NPTS;
        float dd = 0.f, rr = 0.f, sd = 0.f;
        for (int n = t; n < NPTS; n += 256) {
            float di = dv[i * NPTS + n], dj = dv[j * NPTS + n];
            float ri = (xs[i * NPTS + n] - di) * invN;
            float rj = (xs[j * NPTS + n] - dj) * invN;
            dd += di * dj;
            rr += ri * rj;
            sd += di;
        }
        red[t] = make_float4(dd, rr, sd, 0.f);
        __syncthreads();
        for (int h = 128; h > 0; h >>= 1) {
            if (t < h) {
                float4 a = red[t], bb = red[t + h];
                red[t] = make_float4(a.x + bb.x, a.y + bb.y, a.z + bb.z, 0.f);
            }
            __syncthreads();
        }
        if (t == 0) {
            atomicExch(&ddot[p], red[0].x);
            atomicExch(&rdot[p], red[0].y);
            if (i == j)
                atomicExch(&tb[i],
                    (tbss[i] - red[0].z) * (1.0f / ((float)NPTS * (float)NPTS)));
        }
    }

    // ---- last-block finalize (atomic counter; no spinning) ----
    __syncthreads();
    if (t == 0) {
        __threadfence();
        unsigned old = atomicAdd(cnt, 1u);
        lastFlag = (old == NTAIL - 1);
    }
    __syncthreads();
    if (!lastFlag) return;
    __threadfence();
    if (t < ML) tbv[t] = atomicAdd(&tb[t], 0.0f);
    __syncthreads();
    if (t < NPAIR) {
        int i = c_PI[t], j = c_PJ[t];
        double Fv = (double)atomicAdd(&F[t], 0.0f);
        double dd = (double)atomicAdd(&ddot[t], 0.0f);
        double rd = (double)atomicAdd(&rdot[t], 0.0f);
        double v = Fv - dd - 2.0 * (double)NPTS * rd
                 + (double)NPTS * (double)NPTS * (double)tbv[i] * (double)tbv[j];
        hs[i][j] = v; hs[j][i] = v;
    }
    __syncthreads();
    if (t < ML * ML) {
        int i = t / ML, j = t % ML;
        float v;
        if (i == j) v = 1.0f;
        else v = (float)(fabs(hs[i][j]) / sqrt(hs[i][i] * hs[j][j] + 1e-6));
        cka[i][j] = v;
        out[t] = v;
    }
    __syncthreads();
    if (t == 0) {
        float l = 0.f;
        for (int i = 1; i < ML; ++i)
            for (int j = 0; j < i; ++j) l += cka[i][j];   // cka >= 0
        out[ML * ML] = l;
    }
}

extern "C" void kernel_launch(void* const* d_in, const int* in_sizes, int n_in,
                              void* d_out, int out_size, void* d_ws, size_t ws_size,
                              hipStream_t stream) {
    (void)in_sizes; (void)n_in; (void)out_size; (void)ws_size;
    const float* X = (const float*)d_in[0];
    float* out = (float*)d_out;
    char* ws = (char*)d_ws;
    u8*    Xt8 = (u8*)(ws + OFF_XT8);
    float* CP  = (float*)(ws + OFF_CP);
    float* sp  = (float*)(ws + OFF_SP);
    float* dvp = (float*)(ws + OFF_DVP);
    float* F   = (float*)(ws + OFF_F);
    unsigned* cnt = (unsigned*)(ws + OFF_F + 256u);
    float* tbss = (float*)(ws + OFF_F + 512u);
    float* dv  = (float*)(ws + OFF_D);
    float* xs  = (float*)(ws + OFF_XS);
    float* dd  = (float*)(ws + OFF_DD);
    float* rd  = (float*)(ws + OFF_RD);
    float* tb  = (float*)(ws + OFF_T);

    hipLaunchKernelGGL(k_transpose, dim3(64, 8, 6), dim3(256), 0, stream,
                       X, Xt8, sp, dvp, F, cnt, tbss, dv, xs);
    hipLaunchKernelGGL(k_gemm_frob, dim3(NGEMMBLK + NSTATS), dim3(256), 0, stream,
                       Xt8, CP, F, sp, dvp, dv, xs, tbss);
    hipLaunchKernelGGL(k_tail, dim3(NTAIL), dim3(256), 0, stream,
                       CP, dv, xs, tbss, F, dd, rd, tb, cnt, out);
}